// Round 17
// baseline (343.069 us; speedup 1.0000x reference)
//
#include <hip/hip_runtime.h>
#include <hip/hip_bf16.h>
#include <math.h>

#define TSTEPS 128
#define HD 16      // GRU hidden
#define AD 32      // 2*H attention dim
#define CHUNK 8
#define NCHK 16
#define H1W 36     // K2 LDS row width in halfs
#define SEQ_HALFS 4096                   // per-seq history: 16c * 32u * 8

#define SC1 1.44269504088896340736f   // log2(e)   : sigmoid prescale
#define SC2 2.88539008177792681472f   // 2*log2(e) : tanh prescale

typedef _Float16 h4 __attribute__((ext_vector_type(4)));
typedef _Float16 f16x8 __attribute__((ext_vector_type(8)));
typedef float f32x4 __attribute__((ext_vector_type(4)));
typedef float f32x8 __attribute__((ext_vector_type(8)));

#if defined(__has_builtin)
#  if __has_builtin(__builtin_amdgcn_exp2f)
#    define EXP2F(x) __builtin_amdgcn_exp2f(x)
#  endif
#  if __has_builtin(__builtin_amdgcn_rcpf)
#    define RCPF(x) __builtin_amdgcn_rcpf(x)
#  endif
#endif
#ifndef EXP2F
#  define EXP2F(x) exp2f(x)
#endif
#ifndef RCPF
#  define RCPF(x) (1.0f / (x))
#endif

// tanh(x) with pre-scaled input u = 2*log2e*x
__device__ __forceinline__ float tanh_pre(float u) {
    return 1.0f - 2.0f * RCPF(EXP2F(u) + 1.0f);
}

// ---------------- K1: recurrence fully inside the MFMA datapath -------------
// Block = 128 threads = 2 waves; wave0 = fwd, wave1 = bwd over SIXTEEN seqs.
// Lane (sd = lane&15, ug = lane>>4). Columns of every MFMA = the 16 seqs.
//   gx = Wih(+bias ch) . [x_t;1]  : 3x v_mfma_f32_16x16x32_f16 (K=32 >= D+1)
//   gh = Whh . h                  : 3x v_mfma_f32_16x16x16f16  (K=16)
// Documented 16x16x16f16 layouts: B[k=4*ug+e][col=sd], D[row=4*ug+reg][col=sd]
// -> h_new computed in C layout IS next step's B operand: ZERO exchange ops.
// History packed 8 steps in regs, stored per chunk ([seq][c][u32][8], bwd
// chunk-reversed / element-descending exactly like R15 -> K2 unchanged).
template<int D>
__global__ __launch_bounds__(128, 1)
void gru_serial_kernel(
    const float* __restrict__ x,                      // [S, TSTEPS, D]
    const float* __restrict__ Wih_f, const float* __restrict__ Whh_f,
    const float* __restrict__ bih_f, const float* __restrict__ bhh_f,
    const float* __restrict__ Wih_b, const float* __restrict__ Whh_b,
    const float* __restrict__ bih_b, const float* __restrict__ bhh_b,
    _Float16* __restrict__ ghist)
{
    const int tid  = threadIdx.x;
    const int lane = tid & 63;
    const int dir  = tid >> 6;           // wave0 = fwd, wave1 = bwd
    const int sd   = lane & 15;          // seq within block / MFMA column
    const int ug   = lane >> 4;          // unit/k group (0..3)

    const float* WihP = dir ? Wih_b : Wih_f;
    const float* WhhP = dir ? Whh_b : Whh_f;
    const float* bihP = dir ? bih_b : bih_f;
    const float* bhhP = dir ? bhh_b : bhh_f;

    // Whh A-frags (K=16): lane row = gate-in-tile = sd-bits; k = 4*ug+e
    h4 whhA[3];
    #pragma unroll
    for (int n = 0; n < 3; ++n) {
        const float sc = (n < 2) ? SC1 : SC2;
        const int g = 16 * n + sd;
        #pragma unroll
        for (int e = 0; e < 4; ++e)
            whhA[n][e] = (_Float16)(WhhP[g * HD + 4 * ug + e] * sc);
    }
    // Wih A-frags (K=32, bias folded at k==D): k = 8*ug+e
    f16x8 wihA[3];
    #pragma unroll
    for (int n = 0; n < 3; ++n) {
        const float sc = (n < 2) ? SC1 : SC2;
        const int g = 16 * n + sd;
        const float bias = (n < 2) ? (bihP[g] + bhhP[g]) : bihP[g];
        #pragma unroll
        for (int e = 0; e < 8; ++e) {
            const int k = 8 * ug + e;
            wihA[n][e] = (k < D) ? (_Float16)(WihP[g * D + k] * sc)
                       : (k == D) ? (_Float16)(bias * sc)
                       : (_Float16)0.0f;
        }
    }
    // n-gate hidden bias (multiplied by r, can't fold): units 4*ug+e
    float bhn[4];
    #pragma unroll
    for (int e = 0; e < 4; ++e)
        bhn[e] = bhhP[2 * HD + 4 * ug + e] * SC2;

    // this lane's sequence
    const float* xrow = x + (size_t)(blockIdx.x * 16 + sd) * TSTEPS * D;

    // x B-fragment prefetch: raw f32 loads 2 steps deep, cvt 1 step ahead
    auto loadraw = [&](int s) -> f32x8 {
        const int sc_ = (s < TSTEPS) ? s : (TSTEPS - 1);
        const int t = dir ? (TSTEPS - 1 - sc_) : sc_;
        const float* rp = xrow + t * D;
        f32x8 r;
        #pragma unroll
        for (int e = 0; e < 8; ++e) {
            const int k = 8 * ug + e;
            r[e] = (k < D) ? rp[k] : 0.0f;
        }
        return r;
    };
    auto cvtfrag = [&](f32x8 raw) -> f16x8 {
        f16x8 f;
        #pragma unroll
        for (int e = 0; e < 8; ++e) {
            const int k = 8 * ug + e;
            f[e] = (k < D) ? (_Float16)raw[e]
                 : (k == D) ? (_Float16)1.0f : (_Float16)0.0f;
        }
        return f;
    };

    f32x8 rawA = loadraw(0);
    f16x8 fragCur = cvtfrag(rawA);       // step 0
    f32x8 rawB = loadraw(1);

    h4 bcur = (h4){(_Float16)0.0f, (_Float16)0.0f, (_Float16)0.0f, (_Float16)0.0f};
    float hw[4] = {0.0f, 0.0f, 0.0f, 0.0f};

    _Float16* ghbase = ghist + (size_t)(blockIdx.x * 16 + sd) * SEQ_HALFS
                       + (size_t)(dir * 16 + 4 * ug) * 8;

    const f32x4 z4 = {0.f, 0.f, 0.f, 0.f};

    for (int c = 0; c < NCHK; ++c) {
        f16x8 hrow[4];                   // [e][ls], static-indexed (full unroll)

        #pragma unroll
        for (int ls = 0; ls < CHUNK; ++ls) {
            const int s = c * CHUNK + ls;
            // issue raw loads for s+2 into the buffer freed this step
            if ((ls & 1) == 0) rawA = loadraw(s + 2);
            else               rawB = loadraw(s + 2);

            // input-side gates (bias included via k==D channel)
            const f32x4 gxr = __builtin_amdgcn_mfma_f32_16x16x32_f16(wihA[0], fragCur, z4, 0, 0, 0);
            const f32x4 gxz = __builtin_amdgcn_mfma_f32_16x16x32_f16(wihA[1], fragCur, z4, 0, 0, 0);
            const f32x4 gxn = __builtin_amdgcn_mfma_f32_16x16x32_f16(wihA[2], fragCur, z4, 0, 0, 0);
            // hidden-side gates: C layout == next B layout (no exchange)
            const f32x4 ghr = __builtin_amdgcn_mfma_f32_16x16x16f16(whhA[0], bcur, z4, 0, 0, 0);
            const f32x4 ghz = __builtin_amdgcn_mfma_f32_16x16x16f16(whhA[1], bcur, z4, 0, 0, 0);
            const f32x4 ghn = __builtin_amdgcn_mfma_f32_16x16x16f16(whhA[2], bcur, z4, 0, 0, 0);

            #pragma unroll
            for (int e = 0; e < 4; ++e) {
                const float rr = RCPF(1.0f + EXP2F(-(gxr[e] + ghr[e])));
                const float zz = RCPF(1.0f + EXP2F(-(gxz[e] + ghz[e])));
                const float nv = tanh_pre(gxn[e] + rr * (ghn[e] + bhn[e]));
                hw[e] = nv + zz * (hw[e] - nv);
                const _Float16 hh16 = (_Float16)hw[e];
                bcur[e] = hh16;
                hrow[e][ls] = hh16;
            }

            // cvt next step's fragment (raw loaded one step earlier)
            fragCur = cvtfrag((ls & 1) == 0 ? rawB : rawA);
        }

        // store this chunk's history (4x 16B per lane; bwd chunk-reversed)
        const int cc = dir ? (NCHK - 1 - c) : c;
        _Float16* gp = ghbase + (size_t)cc * 256;
        #pragma unroll
        for (int e = 0; e < 4; ++e)
            *reinterpret_cast<f16x8*>(gp + e * 8) = hrow[e];
    }
}

// ---------------- K2: attention over the streamed history (unchanged) ------
template<bool HAS_PROJ>
__global__ __launch_bounds__(128, 4)
void attn_kernel(
    const _Float16* __restrict__ ghist,
    const float* __restrict__ Wa, const float* __restrict__ ba,
    const float* __restrict__ ctxv,
    const float* __restrict__ Wm, const float* __restrict__ bm,
    float* __restrict__ out, int out_cols)
{
    __shared__ __align__(16) _Float16 h1[TSTEPS * H1W];   // 9216 B
    __shared__ float w_sh[TSTEPS];
    __shared__ float red[4];
    __shared__ float cvp[4 * AD];

    const int tid  = threadIdx.x;
    const int lane = tid & 63;
    const int wave = tid >> 6;
    const int seq  = blockIdx.x;

    // stage ghist[seq] -> h1[t][u32]  (coalesced f16x8 loads)
    {
        const f16x8* src = reinterpret_cast<const f16x8*>(ghist + (size_t)seq * SEQ_HALFS);
        #pragma unroll
        for (int k = 0; k < 4; ++k) {
            const int idx = tid + k * 128;
            const f16x8 v = src[idx];
            const int u32 = idx & 31;
            const int tb  = (idx >> 5) * 8;
            const int flip = (u32 >= 16) ? 7 : 0;   // bwd chunks are s-ordered
            #pragma unroll
            for (int e = 0; e < 8; ++e)
                h1[(tb + (e ^ flip)) * H1W + u32] = v[e];
        }
    }
    __syncthreads();

    // tanh proj -> softmax over t
    {
        const int t = tid;
        float hh[AD];
        const h4* hr = reinterpret_cast<const h4*>(&h1[t * H1W]);
        #pragma unroll
        for (int pp = 0; pp < AD / 4; ++pp) {
            const h4 v = hr[pp];
            #pragma unroll
            for (int e = 0; e < 4; ++e) hh[4 * pp + e] = (float)v[e];
        }
        float st = 0.0f;
        for (int i = 0; i < AD; ++i) {
            float a0 = ba[i], a1 = 0.f;
            const float* war = &Wa[i * AD];
            #pragma unroll
            for (int k = 0; k < AD; k += 2) {
                a0 += war[k] * hh[k];
                a1 += war[k + 1] * hh[k + 1];
            }
            st += tanh_pre(SC2 * (a0 + a1)) * ctxv[i];
        }
        float m = st;
        #pragma unroll
        for (int off = 32; off > 0; off >>= 1) m = fmaxf(m, __shfl_xor(m, off));
        if (lane == 0) red[wave] = m;
        __syncthreads();
        m = fmaxf(red[0], red[1]);
        const float e = EXP2F(SC1 * (st - m));
        float ssum = e;
        #pragma unroll
        for (int off = 32; off > 0; off >>= 1) ssum += __shfl_xor(ssum, off);
        if (lane == 0) red[2 + wave] = ssum;
        __syncthreads();
        const float Z = red[2] + red[3];
        w_sh[tid] = e * RCPF(Z);
    }
    __syncthreads();

    // cv[i] = sum_t w[t] * h1[t][i]
    {
        const int g = tid >> 5, i = tid & 31;
        float acc = 0.0f;
        for (int k = 0; k < 32; ++k) {
            const int tt = g * 32 + k;
            acc += w_sh[tt] * (float)h1[tt * H1W + i];
        }
        cvp[g * AD + i] = acc;
    }
    __syncthreads();
    if (tid < AD)
        cvp[tid] = cvp[tid] + cvp[AD + tid] + cvp[2 * AD + tid] + cvp[3 * AD + tid];
    __syncthreads();

    if (HAS_PROJ) {
        if (tid < HD) {
            float acc = bm[tid];
            #pragma unroll
            for (int i = 0; i < AD; ++i) acc += Wm[tid * AD + i] * cvp[i];
            out[(size_t)seq * out_cols + tid] = acc;
        }
    } else {
        if (tid < AD) out[(size_t)seq * out_cols + tid] = cvp[tid];
    }
}

extern "C" void kernel_launch(void* const* d_in, const int* in_sizes, int n_in,
                              void* d_out, int out_size, void* d_ws, size_t ws_size,
                              hipStream_t stream) {
    const float* x     = (const float*)d_in[0];
    const float* Wih1f = (const float*)d_in[1];
    const float* Whh1f = (const float*)d_in[2];
    const float* bih1f = (const float*)d_in[3];
    const float* bhh1f = (const float*)d_in[4];
    const float* Wih1b = (const float*)d_in[5];
    const float* Whh1b = (const float*)d_in[6];
    const float* bih1b = (const float*)d_in[7];
    const float* bhh1b = (const float*)d_in[8];
    const float* Wih2f = (const float*)d_in[9];
    const float* Whh2f = (const float*)d_in[10];
    const float* bih2f = (const float*)d_in[11];
    const float* bhh2f = (const float*)d_in[12];
    const float* Wih2b = (const float*)d_in[13];
    const float* Whh2b = (const float*)d_in[14];
    const float* bih2b = (const float*)d_in[15];
    const float* bhh2b = (const float*)d_in[16];
    const float* Wa1   = (const float*)d_in[17];
    const float* ba1   = (const float*)d_in[18];
    const float* ctx1  = (const float*)d_in[19];
    const float* Wa2   = (const float*)d_in[20];
    const float* ba2   = (const float*)d_in[21];
    const float* ctx2  = (const float*)d_in[22];
    const float* Wm    = (const float*)d_in[23];
    const float* bm    = (const float*)d_in[24];

    float* flow = (float*)d_ws;                               // [8192,16] = 512KB
    const size_t histOff = 1u << 20;                          // 1 MB
    _Float16* ghist = (_Float16*)((char*)d_ws + histOff);     // 64 MB (reused by s2)
    float* outp = (float*)d_out;                              // [64, 32]

    // Stage 1: 8192 seqs, 16 per block -> history; then attention -> flow
    gru_serial_kernel<25><<<512, 128, 0, stream>>>(
        x, Wih1f, Whh1f, bih1f, bhh1f, Wih1b, Whh1b, bih1b, bhh1b, ghist);
    attn_kernel<true><<<8192, 128, 0, stream>>>(
        ghist, Wa1, ba1, ctx1, Wm, bm, flow, 16);

    // Stage 2: 64 seqs (input = flow as [64,128,16]); ghist buffer reused
    gru_serial_kernel<16><<<4, 128, 0, stream>>>(
        flow, Wih2f, Whh2f, bih2f, bhh2f, Wih2b, Whh2b, bih2b, bhh2b, ghist);
    attn_kernel<false><<<64, 128, 0, stream>>>(
        ghist, Wa2, ba2, ctx2, nullptr, nullptr, outp, 32);
}

// Round 18
// 234.852 us; speedup vs baseline: 1.4608x; 1.4608x over previous
//
#include <hip/hip_runtime.h>
#include <hip/hip_bf16.h>
#include <math.h>

#define TSTEPS 128
#define HD 16      // GRU hidden
#define AD 32      // 2*H attention dim
#define CHUNK 8
#define NCHK 16
#define H1W 36     // K2 LDS row width in halfs
#define SEQ_HALFS 4096                   // per-seq history: 16c * 32u * 8

#define SC1 1.44269504088896340736f   // log2(e)   : sigmoid prescale
#define SC2 2.88539008177792681472f   // 2*log2(e) : tanh prescale

typedef _Float16 h4 __attribute__((ext_vector_type(4)));
typedef _Float16 f16x8 __attribute__((ext_vector_type(8)));
typedef float f32x4 __attribute__((ext_vector_type(4)));

#if defined(__has_builtin)
#  if __has_builtin(__builtin_amdgcn_exp2f)
#    define EXP2F(x) __builtin_amdgcn_exp2f(x)
#  endif
#  if __has_builtin(__builtin_amdgcn_rcpf)
#    define RCPF(x) __builtin_amdgcn_rcpf(x)
#  endif
#endif
#ifndef EXP2F
#  define EXP2F(x) exp2f(x)
#endif
#ifndef RCPF
#  define RCPF(x) (1.0f / (x))
#endif

// tanh(x) with pre-scaled input u = 2*log2e*x
__device__ __forceinline__ float tanh_pre(float u) {
    return 1.0f - 2.0f * RCPF(EXP2F(u) + 1.0f);
}

// ---------------- K1: MFMA-datapath recurrence, LDS-fed --------------------
// Block = 128 threads = 2 waves; wave0 = fwd, wave1 = bwd over SIXTEEN seqs.
// Lane (sd = lane&15, ug = lane>>4); MFMA columns = the 16 seqs.
//   gx = Wih(+bias ch) . [x_t;1]  : 3x v_mfma_f32_16x16x32_f16
//   gh = Whh . h                  : 3x v_mfma_f32_16x16x16f16
// C layout of gh step s IS the B layout of step s+1 (verified R17) -> the
// serial chain has ZERO exchange ops. x is staged per-chunk into double-
// buffered LDS by identity copy (contiguous 8-step regions, 16B-aligned since
// t_low % 8 == 0); per-step fragment = 8 ds_read_b32 + pack + keep/bias mask.
template<int D>
__global__ __launch_bounds__(128, 1)
void gru_serial_kernel(
    const float* __restrict__ x,                      // [S, TSTEPS, D]
    const float* __restrict__ Wih_f, const float* __restrict__ Whh_f,
    const float* __restrict__ bih_f, const float* __restrict__ bhh_f,
    const float* __restrict__ Wih_b, const float* __restrict__ Whh_b,
    const float* __restrict__ bih_b, const float* __restrict__ bhh_b,
    _Float16* __restrict__ ghist,
    unsigned long long total_dw)
{
    constexpr int PITCH = (D == 25) ? 212 : 148;     // dwords/seq row (bank-spread)
    constexpr int RDW   = 8 * D;                      // region dwords
    constexpr int LQ    = ((RDW + 15) / 16) * 4;      // per-lane dword span
    constexpr int NLD   = LQ / 4;                     // dwordx4 loads per lane

    __shared__ float xstage[4 * 16 * PITCH];          // [wave][buf][seq][PITCH]

    const int tid  = threadIdx.x;
    const int lane = tid & 63;
    const int dir  = tid >> 6;           // wave0 = fwd, wave1 = bwd
    const int sd   = lane & 15;          // seq within block / MFMA column
    const int ug   = lane >> 4;          // unit/k group (0..3)

    const float* WihP = dir ? Wih_b : Wih_f;
    const float* WhhP = dir ? Whh_b : Whh_f;
    const float* bihP = dir ? bih_b : bih_f;
    const float* bhhP = dir ? bhh_b : bhh_f;

    // Whh A-frags (K=16): row = gate 16n+sd; k = 4*ug+e
    h4 whhA[3];
    #pragma unroll
    for (int n = 0; n < 3; ++n) {
        const float sc = (n < 2) ? SC1 : SC2;
        const int g = 16 * n + sd;
        #pragma unroll
        for (int e = 0; e < 4; ++e)
            whhA[n][e] = (_Float16)(WhhP[g * HD + 4 * ug + e] * sc);
    }
    // Wih A-frags (K=32, bias folded at k==D): k = 8*ug+e
    f16x8 wihA[3];
    #pragma unroll
    for (int n = 0; n < 3; ++n) {
        const float sc = (n < 2) ? SC1 : SC2;
        const int g = 16 * n + sd;
        const float bias = (n < 2) ? (bihP[g] + bhhP[g]) : bihP[g];
        #pragma unroll
        for (int e = 0; e < 8; ++e) {
            const int k = 8 * ug + e;
            wihA[n][e] = (k < D) ? (_Float16)(WihP[g * D + k] * sc)
                       : (k == D) ? (_Float16)(bias * sc)
                       : (_Float16)0.0f;
        }
    }
    // n-gate hidden bias (multiplied by r): units 4*ug+e
    float bhn[4];
    #pragma unroll
    for (int e = 0; e < 4; ++e)
        bhn[e] = bhhP[2 * HD + 4 * ug + e] * SC2;

    // per-lane B-fragment masks: keep (k<D), addv (1.0 at k==D)
    f16x8 keep, addv;
    #pragma unroll
    for (int e = 0; e < 8; ++e) {
        const int k = 8 * ug + e;
        keep[e] = (k < D) ? (_Float16)1.0f : (_Float16)0.0f;
        addv[e] = (k == D) ? (_Float16)1.0f : (_Float16)0.0f;
    }

    // ---- staging roles: 4 lanes per seq ----
    const int sst = lane >> 2, pst = lane & 3;
    const unsigned long long seq_base =
        (unsigned long long)(blockIdx.x * 16 + sst) * (TSTEPS * D);

    float4 st[NLD];
    auto t_low = [&](int c) { return dir ? (TSTEPS - CHUNK - CHUNK * c) : (CHUNK * c); };
    auto stage_load = [&](int c) {
        const unsigned long long rb = seq_base + (unsigned long long)t_low(c) * D;
        #pragma unroll
        for (int j = 0; j < NLD; ++j) {
            unsigned long long off = rb + (unsigned long long)(pst * LQ + 4 * j);
            if (off + 4 > total_dw) off = total_dw - 4;   // array-final clamp
            st[j] = *reinterpret_cast<const float4*>(x + off);
        }
    };
    auto stage_write = [&](int bi) {
        float* wp = xstage + ((dir * 2 + bi) * 16 + sst) * PITCH + pst * LQ;
        #pragma unroll
        for (int j = 0; j < NLD; ++j)
            *reinterpret_cast<float4*>(wp + 4 * j) = st[j];
    };

    h4 bcur = (h4){(_Float16)0.0f, (_Float16)0.0f, (_Float16)0.0f, (_Float16)0.0f};
    float hw[4] = {0.0f, 0.0f, 0.0f, 0.0f};
    _Float16* ghbase = ghist + (unsigned long long)(blockIdx.x * 16 + sd) * SEQ_HALFS
                       + (unsigned long long)(dir * 16 + 4 * ug) * 8;
    const f32x4 z4 = {0.f, 0.f, 0.f, 0.f};
    const int dm = dir ? 7 : 0;          // row = ls ^ dm (7-ls for bwd)

    stage_load(0);
    stage_write(0);

    for (int c = 0; c < NCHK; ++c) {
        if (c + 1 < NCHK) stage_load(c + 1);      // issue-early (T14)

        const float* rdp = xstage + ((dir * 2 + (c & 1)) * 16 + sd) * PITCH + 8 * ug;
        f16x8 hrow[4];

        #pragma unroll
        for (int ls = 0; ls < CHUNK; ++ls) {
            const int row = ls ^ dm;
            const float* rp = rdp + row * D;
            f16x8 frag;
            #pragma unroll
            for (int e = 0; e < 8; ++e)
                frag[e] = (_Float16)rp[e];
            frag = frag * keep + addv;            // mask pads, inject bias ch.

            const f32x4 gxr = __builtin_amdgcn_mfma_f32_16x16x32_f16(wihA[0], frag, z4, 0, 0, 0);
            const f32x4 gxz = __builtin_amdgcn_mfma_f32_16x16x32_f16(wihA[1], frag, z4, 0, 0, 0);
            const f32x4 gxn = __builtin_amdgcn_mfma_f32_16x16x32_f16(wihA[2], frag, z4, 0, 0, 0);
            const f32x4 ghr = __builtin_amdgcn_mfma_f32_16x16x16f16(whhA[0], bcur, z4, 0, 0, 0);
            const f32x4 ghz = __builtin_amdgcn_mfma_f32_16x16x16f16(whhA[1], bcur, z4, 0, 0, 0);
            const f32x4 ghn = __builtin_amdgcn_mfma_f32_16x16x16f16(whhA[2], bcur, z4, 0, 0, 0);

            #pragma unroll
            for (int e = 0; e < 4; ++e) {
                const float rr = RCPF(1.0f + EXP2F(-(gxr[e] + ghr[e])));
                const float zz = RCPF(1.0f + EXP2F(-(gxz[e] + ghz[e])));
                const float nv = tanh_pre(gxn[e] + rr * (ghn[e] + bhn[e]));
                hw[e] = nv + zz * (hw[e] - nv);
                const _Float16 hh16 = (_Float16)hw[e];
                bcur[e] = hh16;
                hrow[e][ls] = hh16;
            }
        }

        // history store: 4x 16B per lane; bwd chunk-reversed (K2-compatible)
        const int cc = dir ? (NCHK - 1 - c) : c;
        _Float16* gp = ghbase + (unsigned long long)cc * 256;
        #pragma unroll
        for (int e = 0; e < 4; ++e)
            *reinterpret_cast<f16x8*>(gp + e * 8) = hrow[e];

        if (c + 1 < NCHK) stage_write((c + 1) & 1);   // write-late (T14)
    }
}

// ---------------- K2: attention over the streamed history (unchanged) ------
template<bool HAS_PROJ>
__global__ __launch_bounds__(128, 4)
void attn_kernel(
    const _Float16* __restrict__ ghist,
    const float* __restrict__ Wa, const float* __restrict__ ba,
    const float* __restrict__ ctxv,
    const float* __restrict__ Wm, const float* __restrict__ bm,
    float* __restrict__ out, int out_cols)
{
    __shared__ __align__(16) _Float16 h1[TSTEPS * H1W];   // 9216 B
    __shared__ float w_sh[TSTEPS];
    __shared__ float red[4];
    __shared__ float cvp[4 * AD];

    const int tid  = threadIdx.x;
    const int lane = tid & 63;
    const int wave = tid >> 6;
    const int seq  = blockIdx.x;

    // stage ghist[seq] -> h1[t][u32]  (coalesced f16x8 loads)
    {
        const f16x8* src = reinterpret_cast<const f16x8*>(ghist + (size_t)seq * SEQ_HALFS);
        #pragma unroll
        for (int k = 0; k < 4; ++k) {
            const int idx = tid + k * 128;
            const f16x8 v = src[idx];
            const int u32 = idx & 31;
            const int tb  = (idx >> 5) * 8;
            const int flip = (u32 >= 16) ? 7 : 0;   // bwd chunks are s-ordered
            #pragma unroll
            for (int e = 0; e < 8; ++e)
                h1[(tb + (e ^ flip)) * H1W + u32] = v[e];
        }
    }
    __syncthreads();

    // tanh proj -> softmax over t
    {
        const int t = tid;
        float hh[AD];
        const h4* hr = reinterpret_cast<const h4*>(&h1[t * H1W]);
        #pragma unroll
        for (int pp = 0; pp < AD / 4; ++pp) {
            const h4 v = hr[pp];
            #pragma unroll
            for (int e = 0; e < 4; ++e) hh[4 * pp + e] = (float)v[e];
        }
        float st = 0.0f;
        for (int i = 0; i < AD; ++i) {
            float a0 = ba[i], a1 = 0.f;
            const float* war = &Wa[i * AD];
            #pragma unroll
            for (int k = 0; k < AD; k += 2) {
                a0 += war[k] * hh[k];
                a1 += war[k + 1] * hh[k + 1];
            }
            st += tanh_pre(SC2 * (a0 + a1)) * ctxv[i];
        }
        float m = st;
        #pragma unroll
        for (int off = 32; off > 0; off >>= 1) m = fmaxf(m, __shfl_xor(m, off));
        if (lane == 0) red[wave] = m;
        __syncthreads();
        m = fmaxf(red[0], red[1]);
        const float e = EXP2F(SC1 * (st - m));
        float ssum = e;
        #pragma unroll
        for (int off = 32; off > 0; off >>= 1) ssum += __shfl_xor(ssum, off);
        if (lane == 0) red[2 + wave] = ssum;
        __syncthreads();
        const float Z = red[2] + red[3];
        w_sh[tid] = e * RCPF(Z);
    }
    __syncthreads();

    // cv[i] = sum_t w[t] * h1[t][i]
    {
        const int g = tid >> 5, i = tid & 31;
        float acc = 0.0f;
        for (int k = 0; k < 32; ++k) {
            const int tt = g * 32 + k;
            acc += w_sh[tt] * (float)h1[tt * H1W + i];
        }
        cvp[g * AD + i] = acc;
    }
    __syncthreads();
    if (tid < AD)
        cvp[tid] = cvp[tid] + cvp[AD + tid] + cvp[2 * AD + tid] + cvp[3 * AD + tid];
    __syncthreads();

    if (HAS_PROJ) {
        if (tid < HD) {
            float acc = bm[tid];
            #pragma unroll
            for (int i = 0; i < AD; ++i) acc += Wm[tid * AD + i] * cvp[i];
            out[(size_t)seq * out_cols + tid] = acc;
        }
    } else {
        if (tid < AD) out[(size_t)seq * out_cols + tid] = cvp[tid];
    }
}

extern "C" void kernel_launch(void* const* d_in, const int* in_sizes, int n_in,
                              void* d_out, int out_size, void* d_ws, size_t ws_size,
                              hipStream_t stream) {
    const float* x     = (const float*)d_in[0];
    const float* Wih1f = (const float*)d_in[1];
    const float* Whh1f = (const float*)d_in[2];
    const float* bih1f = (const float*)d_in[3];
    const float* bhh1f = (const float*)d_in[4];
    const float* Wih1b = (const float*)d_in[5];
    const float* Whh1b = (const float*)d_in[6];
    const float* bih1b = (const float*)d_in[7];
    const float* bhh1b = (const float*)d_in[8];
    const float* Wih2f = (const float*)d_in[9];
    const float* Whh2f = (const float*)d_in[10];
    const float* bih2f = (const float*)d_in[11];
    const float* bhh2f = (const float*)d_in[12];
    const float* Wih2b = (const float*)d_in[13];
    const float* Whh2b = (const float*)d_in[14];
    const float* bih2b = (const float*)d_in[15];
    const float* bhh2b = (const float*)d_in[16];
    const float* Wa1   = (const float*)d_in[17];
    const float* ba1   = (const float*)d_in[18];
    const float* ctx1  = (const float*)d_in[19];
    const float* Wa2   = (const float*)d_in[20];
    const float* ba2   = (const float*)d_in[21];
    const float* ctx2  = (const float*)d_in[22];
    const float* Wm    = (const float*)d_in[23];
    const float* bm    = (const float*)d_in[24];

    float* flow = (float*)d_ws;                               // [8192,16] = 512KB
    const size_t histOff = 1u << 20;                          // 1 MB
    _Float16* ghist = (_Float16*)((char*)d_ws + histOff);     // 64 MB (reused by s2)
    float* outp = (float*)d_out;                              // [64, 32]

    // Stage 1: 8192 seqs, 16 per block -> history; then attention -> flow
    gru_serial_kernel<25><<<512, 128, 0, stream>>>(
        x, Wih1f, Whh1f, bih1f, bhh1f, Wih1b, Whh1b, bih1b, bhh1b, ghist,
        (unsigned long long)8192 * TSTEPS * 25);
    attn_kernel<true><<<8192, 128, 0, stream>>>(
        ghist, Wa1, ba1, ctx1, Wm, bm, flow, 16);

    // Stage 2: 64 seqs (input = flow as [64,128,16]); ghist buffer reused
    gru_serial_kernel<16><<<4, 128, 0, stream>>>(
        flow, Wih2f, Whh2f, bih2f, bhh2f, Wih2b, Whh2b, bih2b, bhh2b, ghist,
        (unsigned long long)64 * TSTEPS * 16);
    attn_kernel<false><<<64, 128, 0, stream>>>(
        ghist, Wa2, ba2, ctx2, nullptr, nullptr, outp, 32);
}

// Round 19
// 166.909 us; speedup vs baseline: 2.0554x; 1.4071x over previous
//
#include <hip/hip_runtime.h>
#include <hip/hip_bf16.h>
#include <math.h>

#define TSTEPS 128
#define HD 16      // GRU hidden
#define AD 32      // 2*H attention dim
#define CHUNK 8
#define NCHK 16
#define H1W 36     // K2 LDS row width in halfs
#define SEQ_HALFS 4096                   // per-seq history: 16c * 32u * 8
#define PH 264     // xstage halfs per seq region (528B, 16B-aligned rows)

#define SC1 1.44269504088896340736f   // log2(e)   : sigmoid prescale
#define SC2 2.88539008177792681472f   // 2*log2(e) : tanh prescale

typedef _Float16 h4 __attribute__((ext_vector_type(4)));
typedef _Float16 f16x8 __attribute__((ext_vector_type(8)));
typedef float f32x4 __attribute__((ext_vector_type(4)));

#if defined(__has_builtin)
#  if __has_builtin(__builtin_amdgcn_exp2f)
#    define EXP2F(x) __builtin_amdgcn_exp2f(x)
#  endif
#  if __has_builtin(__builtin_amdgcn_rcpf)
#    define RCPF(x) __builtin_amdgcn_rcpf(x)
#  endif
#endif
#ifndef EXP2F
#  define EXP2F(x) exp2f(x)
#endif
#ifndef RCPF
#  define RCPF(x) (1.0f / (x))
#endif

// tanh(x) with pre-scaled input u = 2*log2e*x
__device__ __forceinline__ float tanh_pre(float u) {
    return 1.0f - 2.0f * RCPF(EXP2F(u) + 1.0f);
}

// pack one padded f16 row: [0..D) = data, [D] = 1.0 (bias ch.), rest = 0
template<int D>
__device__ __forceinline__ void store_row(_Float16* wp, const float* v) {
    #pragma unroll
    for (int part = 0; part < 4; ++part) {
        f16x8 w;
        #pragma unroll
        for (int e = 0; e < 8; ++e) {
            const int k = part * 8 + e;
            w[e] = (k < D) ? (_Float16)v[k]
                 : (k == D) ? (_Float16)1.0f : (_Float16)0.0f;
        }
        *reinterpret_cast<f16x8*>(wp + part * 8) = w;
    }
}

// ---------------- K1: MFMA-datapath recurrence, f16-LDS-fed ----------------
// Block = 128 threads = 2 waves; wave0 = fwd, wave1 = bwd over SIXTEEN seqs.
// Lane (sd = lane&15, ug = lane>>4); MFMA columns = the 16 seqs.
//   gx = Wih(+bias ch) . [x_t;1]  : 3x v_mfma_f32_16x16x32_f16
//   gh = Whh . h                  : 3x v_mfma_f32_16x16x16f16
// C layout of gh step s IS the B layout of step s+1 (verified R17/R18) -> the
// serial chain is 3 MFMAs + activations only. x rows are staged per-chunk as
// PRE-MASKED f16 rows (32 halfs: data, bias=1.0 at [D], zero pad) -> per-step
// B-fragment is ONE ds_read_b128. Staging: 2 rows/lane, scalar loads (rows
// are not 16B-aligned), plain static arrays, NO lambdas (R18's scratch bug).
template<int D>
__global__ __launch_bounds__(128, 1)
void gru_serial_kernel(
    const float* __restrict__ x,                      // [S, TSTEPS, D]
    const float* __restrict__ Wih_f, const float* __restrict__ Whh_f,
    const float* __restrict__ bih_f, const float* __restrict__ bhh_f,
    const float* __restrict__ Wih_b, const float* __restrict__ Whh_b,
    const float* __restrict__ bih_b, const float* __restrict__ bhh_b,
    _Float16* __restrict__ ghist)
{
    __shared__ __align__(16) _Float16 xstage[2 * 2 * 16 * PH];   // 33792 B

    const int tid  = threadIdx.x;
    const int lane = tid & 63;
    const int dir  = tid >> 6;           // wave0 = fwd, wave1 = bwd
    const int sd   = lane & 15;          // seq within block / MFMA column
    const int ug   = lane >> 4;          // unit/k group (0..3)

    const float* WihP = dir ? Wih_b : Wih_f;
    const float* WhhP = dir ? Whh_b : Whh_f;
    const float* bihP = dir ? bih_b : bih_f;
    const float* bhhP = dir ? bhh_b : bhh_f;

    // Whh A-frags (K=16): row = gate 16n+sd; k = 4*ug+e
    h4 whhA[3];
    #pragma unroll
    for (int n = 0; n < 3; ++n) {
        const float sc = (n < 2) ? SC1 : SC2;
        const int g = 16 * n + sd;
        #pragma unroll
        for (int e = 0; e < 4; ++e)
            whhA[n][e] = (_Float16)(WhhP[g * HD + 4 * ug + e] * sc);
    }
    // Wih A-frags (K=32, bias value at k==D): k = 8*ug+e
    f16x8 wihA[3];
    #pragma unroll
    for (int n = 0; n < 3; ++n) {
        const float sc = (n < 2) ? SC1 : SC2;
        const int g = 16 * n + sd;
        const float bias = (n < 2) ? (bihP[g] + bhhP[g]) : bihP[g];
        #pragma unroll
        for (int e = 0; e < 8; ++e) {
            const int k = 8 * ug + e;
            wihA[n][e] = (k < D) ? (_Float16)(WihP[g * D + k] * sc)
                       : (k == D) ? (_Float16)(bias * sc)
                       : (_Float16)0.0f;
        }
    }
    // n-gate hidden bias (multiplied by r): units 4*ug+e
    float bhn[4];
    #pragma unroll
    for (int e = 0; e < 4; ++e)
        bhn[e] = bhhP[2 * HD + 4 * ug + e] * SC2;

    // ---- staging roles: 4 lanes per seq, 2 rows per lane ----
    const int sst = lane >> 2;
    const int pst = lane & 3;
    const int ls0 = 2 * pst, ls1 = ls0 + 1;
    const float* xseq = x + (size_t)(blockIdx.x * 16 + sst) * (TSTEPS * D);

    _Float16* mybuf = xstage + dir * (2 * 16 * PH);
    _Float16* wpr0  = mybuf + sst * PH + ls0 * 32;    // + bufsel*16*PH
    _Float16* wpr1  = mybuf + sst * PH + ls1 * 32;

    // prologue: stage chunk 0 into buf 0
    {
        const int t0 = dir ? (TSTEPS - 1 - ls0) : ls0;
        const int t1 = dir ? (TSTEPS - 1 - ls1) : ls1;
        const float* r0 = xseq + (size_t)t0 * D;
        const float* r1 = xseq + (size_t)t1 * D;
        float rA[D], rB[D];
        #pragma unroll
        for (int k = 0; k < D; ++k) { rA[k] = r0[k]; rB[k] = r1[k]; }
        store_row<D>(wpr0, rA);
        store_row<D>(wpr1, rB);
    }

    h4 bcur = (h4){(_Float16)0.0f, (_Float16)0.0f, (_Float16)0.0f, (_Float16)0.0f};
    float hw[4] = {0.0f, 0.0f, 0.0f, 0.0f};
    _Float16* ghbase = ghist + (size_t)(blockIdx.x * 16 + sd) * SEQ_HALFS
                       + (size_t)(dir * 16 + 4 * ug) * 8;
    const f32x4 z4 = {0.f, 0.f, 0.f, 0.f};

    #pragma unroll 1
    for (int c = 0; c < NCHK; ++c) {
        // issue next chunk's row loads early (scalar; covered by 8 steps)
        float rA[D], rB[D];
        if (c + 1 < NCHK) {
            const int s0 = (c + 1) * CHUNK + ls0;
            const int s1 = (c + 1) * CHUNK + ls1;
            const int t0 = dir ? (TSTEPS - 1 - s0) : s0;
            const int t1 = dir ? (TSTEPS - 1 - s1) : s1;
            const float* r0 = xseq + (size_t)t0 * D;
            const float* r1 = xseq + (size_t)t1 * D;
            #pragma unroll
            for (int k = 0; k < D; ++k) { rA[k] = r0[k]; rB[k] = r1[k]; }
        }

        const _Float16* rdp = mybuf + (c & 1) * (16 * PH) + sd * PH + ug * 8;
        f16x8 hrow[4];

        // serial 8 steps: 1 ds_read_b128 + 6 MFMA + activations
        #pragma unroll
        for (int ls = 0; ls < CHUNK; ++ls) {
            const f16x8 frag = *reinterpret_cast<const f16x8*>(rdp + ls * 32);

            const f32x4 gxr = __builtin_amdgcn_mfma_f32_16x16x32_f16(wihA[0], frag, z4, 0, 0, 0);
            const f32x4 gxz = __builtin_amdgcn_mfma_f32_16x16x32_f16(wihA[1], frag, z4, 0, 0, 0);
            const f32x4 gxn = __builtin_amdgcn_mfma_f32_16x16x32_f16(wihA[2], frag, z4, 0, 0, 0);
            const f32x4 ghr = __builtin_amdgcn_mfma_f32_16x16x16f16(whhA[0], bcur, z4, 0, 0, 0);
            const f32x4 ghz = __builtin_amdgcn_mfma_f32_16x16x16f16(whhA[1], bcur, z4, 0, 0, 0);
            const f32x4 ghn = __builtin_amdgcn_mfma_f32_16x16x16f16(whhA[2], bcur, z4, 0, 0, 0);

            #pragma unroll
            for (int e = 0; e < 4; ++e) {
                const float rr = RCPF(1.0f + EXP2F(-(gxr[e] + ghr[e])));
                const float zz = RCPF(1.0f + EXP2F(-(gxz[e] + ghz[e])));
                const float nv = tanh_pre(gxn[e] + rr * (ghn[e] + bhn[e]));
                hw[e] = nv + zz * (hw[e] - nv);
                const _Float16 hh16 = (_Float16)hw[e];
                bcur[e] = hh16;
                hrow[e][ls] = hh16;
            }
        }

        // history store: 4x 16B contiguous per lane; bwd chunk-reversed
        const int cc = dir ? (NCHK - 1 - c) : c;
        _Float16* gp = ghbase + (size_t)cc * 256;
        #pragma unroll
        for (int e = 0; e < 4; ++e)
            *reinterpret_cast<f16x8*>(gp + e * 8) = hrow[e];

        // convert + write next chunk's rows (write-late)
        if (c + 1 < NCHK) {
            const int bs = ((c + 1) & 1) * (16 * PH);
            store_row<D>(wpr0 + bs, rA);
            store_row<D>(wpr1 + bs, rB);
        }
    }
}

// ---------------- K2: attention over the streamed history (unchanged) ------
template<bool HAS_PROJ>
__global__ __launch_bounds__(128, 4)
void attn_kernel(
    const _Float16* __restrict__ ghist,
    const float* __restrict__ Wa, const float* __restrict__ ba,
    const float* __restrict__ ctxv,
    const float* __restrict__ Wm, const float* __restrict__ bm,
    float* __restrict__ out, int out_cols)
{
    __shared__ __align__(16) _Float16 h1[TSTEPS * H1W];   // 9216 B
    __shared__ float w_sh[TSTEPS];
    __shared__ float red[4];
    __shared__ float cvp[4 * AD];

    const int tid  = threadIdx.x;
    const int lane = tid & 63;
    const int wave = tid >> 6;
    const int seq  = blockIdx.x;

    // stage ghist[seq] -> h1[t][u32]  (coalesced f16x8 loads)
    {
        const f16x8* src = reinterpret_cast<const f16x8*>(ghist + (size_t)seq * SEQ_HALFS);
        #pragma unroll
        for (int k = 0; k < 4; ++k) {
            const int idx = tid + k * 128;
            const f16x8 v = src[idx];
            const int u32 = idx & 31;
            const int tb  = (idx >> 5) * 8;
            const int flip = (u32 >= 16) ? 7 : 0;   // bwd chunks are s-ordered
            #pragma unroll
            for (int e = 0; e < 8; ++e)
                h1[(tb + (e ^ flip)) * H1W + u32] = v[e];
        }
    }
    __syncthreads();

    // tanh proj -> softmax over t
    {
        const int t = tid;
        float hh[AD];
        const h4* hr = reinterpret_cast<const h4*>(&h1[t * H1W]);
        #pragma unroll
        for (int pp = 0; pp < AD / 4; ++pp) {
            const h4 v = hr[pp];
            #pragma unroll
            for (int e = 0; e < 4; ++e) hh[4 * pp + e] = (float)v[e];
        }
        float st = 0.0f;
        for (int i = 0; i < AD; ++i) {
            float a0 = ba[i], a1 = 0.f;
            const float* war = &Wa[i * AD];
            #pragma unroll
            for (int k = 0; k < AD; k += 2) {
                a0 += war[k] * hh[k];
                a1 += war[k + 1] * hh[k + 1];
            }
            st += tanh_pre(SC2 * (a0 + a1)) * ctxv[i];
        }
        float m = st;
        #pragma unroll
        for (int off = 32; off > 0; off >>= 1) m = fmaxf(m, __shfl_xor(m, off));
        if (lane == 0) red[wave] = m;
        __syncthreads();
        m = fmaxf(red[0], red[1]);
        const float e = EXP2F(SC1 * (st - m));
        float ssum = e;
        #pragma unroll
        for (int off = 32; off > 0; off >>= 1) ssum += __shfl_xor(ssum, off);
        if (lane == 0) red[2 + wave] = ssum;
        __syncthreads();
        const float Z = red[2] + red[3];
        w_sh[tid] = e * RCPF(Z);
    }
    __syncthreads();

    // cv[i] = sum_t w[t] * h1[t][i]
    {
        const int g = tid >> 5, i = tid & 31;
        float acc = 0.0f;
        for (int k = 0; k < 32; ++k) {
            const int tt = g * 32 + k;
            acc += w_sh[tt] * (float)h1[tt * H1W + i];
        }
        cvp[g * AD + i] = acc;
    }
    __syncthreads();
    if (tid < AD)
        cvp[tid] = cvp[tid] + cvp[AD + tid] + cvp[2 * AD + tid] + cvp[3 * AD + tid];
    __syncthreads();

    if (HAS_PROJ) {
        if (tid < HD) {
            float acc = bm[tid];
            #pragma unroll
            for (int i = 0; i < AD; ++i) acc += Wm[tid * AD + i] * cvp[i];
            out[(size_t)seq * out_cols + tid] = acc;
        }
    } else {
        if (tid < AD) out[(size_t)seq * out_cols + tid] = cvp[tid];
    }
}

extern "C" void kernel_launch(void* const* d_in, const int* in_sizes, int n_in,
                              void* d_out, int out_size, void* d_ws, size_t ws_size,
                              hipStream_t stream) {
    const float* x     = (const float*)d_in[0];
    const float* Wih1f = (const float*)d_in[1];
    const float* Whh1f = (const float*)d_in[2];
    const float* bih1f = (const float*)d_in[3];
    const float* bhh1f = (const float*)d_in[4];
    const float* Wih1b = (const float*)d_in[5];
    const float* Whh1b = (const float*)d_in[6];
    const float* bih1b = (const float*)d_in[7];
    const float* bhh1b = (const float*)d_in[8];
    const float* Wih2f = (const float*)d_in[9];
    const float* Whh2f = (const float*)d_in[10];
    const float* bih2f = (const float*)d_in[11];
    const float* bhh2f = (const float*)d_in[12];
    const float* Wih2b = (const float*)d_in[13];
    const float* Whh2b = (const float*)d_in[14];
    const float* bih2b = (const float*)d_in[15];
    const float* bhh2b = (const float*)d_in[16];
    const float* Wa1   = (const float*)d_in[17];
    const float* ba1   = (const float*)d_in[18];
    const float* ctx1  = (const float*)d_in[19];
    const float* Wa2   = (const float*)d_in[20];
    const float* ba2   = (const float*)d_in[21];
    const float* ctx2  = (const float*)d_in[22];
    const float* Wm    = (const float*)d_in[23];
    const float* bm    = (const float*)d_in[24];

    float* flow = (float*)d_ws;                               // [8192,16] = 512KB
    const size_t histOff = 1u << 20;                          // 1 MB
    _Float16* ghist = (_Float16*)((char*)d_ws + histOff);     // 64 MB (reused by s2)
    float* outp = (float*)d_out;                              // [64, 32]

    // Stage 1: 8192 seqs, 16 per block -> history; then attention -> flow
    gru_serial_kernel<25><<<512, 128, 0, stream>>>(
        x, Wih1f, Whh1f, bih1f, bhh1f, Wih1b, Whh1b, bih1b, bhh1b, ghist);
    attn_kernel<true><<<8192, 128, 0, stream>>>(
        ghist, Wa1, ba1, ctx1, Wm, bm, flow, 16);

    // Stage 2: 64 seqs (input = flow as [64,128,16]); ghist buffer reused
    gru_serial_kernel<16><<<4, 128, 0, stream>>>(
        flow, Wih2f, Whh2f, bih2f, bhh2f, Wih2b, Whh2b, bih2b, bhh2b, ghist);
    attn_kernel<false><<<64, 128, 0, stream>>>(
        ghist, Wa2, ba2, ctx2, nullptr, nullptr, outp, 32);
}